// Round 1
// baseline (734.509 us; speedup 1.0000x reference)
//
#include <hip/hip_runtime.h>
#include <hip/hip_bf16.h>

// Problem constants (from reference)
#define M_TOK 256
#define K_DIM 1024
#define N_DIM 2048
#define NE    64
#define TOPKK 8
#define L_ROWS (M_TOK * TOPKK)   // 2048
#define CAP    (L_ROWS / NE)     // 32 rows per expert (balanced routing)

// GEMM tile config
#define BN  128
#define BK  64
#define LDK (BK + 8)             // +8 bf16 pad -> 2-way max LDS aliasing (free)

typedef __bf16 bf16x8 __attribute__((ext_vector_type(8)));
typedef float  f32x4  __attribute__((ext_vector_type(4)));

// ---------------------------------------------------------------------------
// Routing: one wave per expert; ballot-compact the slots (m*TOPK+t) whose
// topk_id == expert into ws[e*CAP .. e*CAP+31]. Order within expert is
// irrelevant for correctness (each slot writes its own output row).
// ---------------------------------------------------------------------------
__global__ void route_kernel(const int* __restrict__ ids, int* __restrict__ slots) {
    int e    = blockIdx.x;
    int lane = threadIdx.x;           // 0..63
    int base = 0;
    for (int c = 0; c < L_ROWS; c += 64) {
        int slot = c + lane;
        bool match = (ids[slot] == e);
        unsigned long long mask = __ballot(match);
        int pos = __popcll(mask & ((1ULL << lane) - 1ULL));
        if (match) slots[e * CAP + base + pos] = slot;
        base += __popcll(mask);
    }
}

__device__ inline void cvt_store4(__bf16* dst, float4 v) {
    dst[0] = (__bf16)v.x; dst[1] = (__bf16)v.y;
    dst[2] = (__bf16)v.z; dst[3] = (__bf16)v.w;
}

// ---------------------------------------------------------------------------
// Grouped GEMM: block = (expert e, N-tile of 128). BM=32 tokens (the expert's
// full set), K streamed in BK=64 chunks through bf16 LDS, 16x16x32 bf16 MFMA.
// 4 waves: wave w owns N columns [w*32, w*32+32), full M=32 -> 4 acc tiles.
// ---------------------------------------------------------------------------
__global__ __launch_bounds__(256, 2) void moe_gemm(
    const float* __restrict__ A,      // [M_TOK, K]
    const float* __restrict__ B,      // [E, N, K]
    const float* __restrict__ bias,   // [E, N]
    const float* __restrict__ tw,     // [M_TOK, TOPK] flat
    const int*   __restrict__ slots,  // [E, CAP]
    float*       __restrict__ out)    // [L_ROWS, N]
{
    const int e  = blockIdx.x >> 4;          // 2048/128 = 16 tiles per expert
    const int n0 = (blockIdx.x & 15) * BN;

    __shared__ __bf16 sA[32 * LDK];
    __shared__ __bf16 sB[BN * LDK];
    __shared__ int    sSlot[CAP];
    __shared__ float  sW[CAP];

    const int t = threadIdx.x;
    if (t < CAP) {
        int s = slots[e * CAP + t];
        sSlot[t] = s;
        sW[t]    = tw[s];
    }
    __syncthreads();

    // Staging assignment: 256 threads; idx = t + i*256; row = idx>>4, k4 = idx&15
    const int rA = t >> 4;        // A row this thread stages (and rA+16)
    const int k4 = t & 15;        // float4 index within BK=64 (16 float4/row)

    const int tok0 = sSlot[rA] >> 3;        // TOPK = 8
    const int tok1 = sSlot[rA + 16] >> 3;
    const float* aPtr0 = A + (size_t)tok0 * K_DIM + k4 * 4;
    const float* aPtr1 = A + (size_t)tok1 * K_DIM + k4 * 4;
    const float* bPtr  = B + ((size_t)e * N_DIM + n0 + rA) * K_DIM + k4 * 4;

    const int wv   = t >> 6;       // wave id 0..3
    const int lane = t & 63;
    const int fr   = lane & 15;    // fragment row (m for A-frag, n for B-frag)
    const int kg   = lane >> 4;    // k-group 0..3

    f32x4 acc[2][2] = {{{0.f,0.f,0.f,0.f},{0.f,0.f,0.f,0.f}},
                       {{0.f,0.f,0.f,0.f},{0.f,0.f,0.f,0.f}}};

    for (int k0 = 0; k0 < K_DIM; k0 += BK) {
        // ---- global fp32 loads (coalesced float4) ----
        float4 av0 = *(const float4*)(aPtr0 + k0);
        float4 av1 = *(const float4*)(aPtr1 + k0);
        float4 bv[8];
        #pragma unroll
        for (int i = 0; i < 8; i++)
            bv[i] = *(const float4*)(bPtr + (size_t)i * 16 * K_DIM + k0);

        // ---- convert to bf16, stage to LDS ----
        cvt_store4(&sA[rA        * LDK + k4 * 4], av0);
        cvt_store4(&sA[(rA + 16) * LDK + k4 * 4], av1);
        #pragma unroll
        for (int i = 0; i < 8; i++)
            cvt_store4(&sB[(rA + i * 16) * LDK + k4 * 4], bv[i]);
        __syncthreads();

        // ---- MFMA over the BK=64 chunk (two K=32 steps) ----
        #pragma unroll
        for (int kk = 0; kk < 2; kk++) {
            const int koff = kg * 8 + kk * 32;
            bf16x8 a0 = *(const bf16x8*)&sA[fr        * LDK + koff];
            bf16x8 a1 = *(const bf16x8*)&sA[(fr + 16) * LDK + koff];
            bf16x8 b0 = *(const bf16x8*)&sB[(wv * 32 + fr)      * LDK + koff];
            bf16x8 b1 = *(const bf16x8*)&sB[(wv * 32 + 16 + fr) * LDK + koff];
            acc[0][0] = __builtin_amdgcn_mfma_f32_16x16x32_bf16(a0, b0, acc[0][0], 0, 0, 0);
            acc[0][1] = __builtin_amdgcn_mfma_f32_16x16x32_bf16(a0, b1, acc[0][1], 0, 0, 0);
            acc[1][0] = __builtin_amdgcn_mfma_f32_16x16x32_bf16(a1, b0, acc[1][0], 0, 0, 0);
            acc[1][1] = __builtin_amdgcn_mfma_f32_16x16x32_bf16(a1, b1, acc[1][1], 0, 0, 0);
        }
        __syncthreads();
    }

    // ---- epilogue: (acc + bias[e][n]) * tw[slot] -> out[slot][n] ----
    // C/D layout (16x16x32): col = lane&15, row = (lane>>4)*4 + reg
    const int nl0 = n0 + wv * 32 + fr;
    const float bias0 = bias[(size_t)e * N_DIM + nl0];
    const float bias1 = bias[(size_t)e * N_DIM + nl0 + 16];

    #pragma unroll
    for (int mt = 0; mt < 2; mt++) {
        #pragma unroll
        for (int r = 0; r < 4; r++) {
            const int m    = mt * 16 + kg * 4 + r;
            const int slot = sSlot[m];
            const float wg = sW[m];
            out[(size_t)slot * N_DIM + nl0]      = (acc[mt][0][r] + bias0) * wg;
            out[(size_t)slot * N_DIM + nl0 + 16] = (acc[mt][1][r] + bias1) * wg;
        }
    }
}

extern "C" void kernel_launch(void* const* d_in, const int* in_sizes, int n_in,
                              void* d_out, int out_size, void* d_ws, size_t ws_size,
                              hipStream_t stream) {
    const float* A    = (const float*)d_in[0];   // [256,1024]
    const float* B    = (const float*)d_in[1];   // [64,2048,1024]
    const float* bias = (const float*)d_in[2];   // [64,2048]
    const float* tw   = (const float*)d_in[3];   // [256,8]
    const int*   ids  = (const int*)d_in[4];     // [256,8]
    float* out  = (float*)d_out;                 // [256,8,2048]
    int* slots  = (int*)d_ws;                    // E*CAP = 2048 ints

    route_kernel<<<NE, 64, 0, stream>>>(ids, slots);
    moe_gemm<<<NE * 16, 256, 0, stream>>>(A, B, bias, tw, slots, out);
}